// Round 1
// baseline (19105.675 us; speedup 1.0000x reference)
//
#include <hip/hip_runtime.h>

// Problem constants (match reference)
#define BB 16
#define SS 2048
#define DD 256
#define ND4 1024   // 4*D
#define LL 4

// ---------------------------------------------------------------------------
// Kernel 1: embed  h0[tok][d] = x[tok]*in_W[0][d] + sum_c tf[tok][c]*in_W[c+1][d] + in_b[d]
// ---------------------------------------------------------------------------
__global__ void embed_kernel(const float* __restrict__ x, const float* __restrict__ tf,
                             const float* __restrict__ inW, const float* __restrict__ inb,
                             float* __restrict__ h) {
    int tok = blockIdx.x;
    int d = threadIdx.x;
    float xv = x[tok];
    float acc = inb[d] + xv * inW[d];
#pragma unroll
    for (int c = 0; c < 6; ++c)
        acc = fmaf(tf[tok * 6 + c], inW[(c + 1) * DD + d], acc);
    h[(size_t)tok * DD + d] = acc;
}

// ---------------------------------------------------------------------------
// Kernel 2: per-token LN stats (biased var, matches jnp.var ddof=0)
// one wave (64 lanes) per token, 4 tokens per 256-thread block
// ---------------------------------------------------------------------------
__global__ void ln_stats_kernel(const float* __restrict__ h, float* __restrict__ mu,
                                float* __restrict__ rs) {
    int wave = threadIdx.x >> 6, lane = threadIdx.x & 63;
    int tok = blockIdx.x * 4 + wave;
    const float4 v = *(const float4*)(h + (size_t)tok * DD + lane * 4);
    float s = v.x + v.y + v.z + v.w;
    float ss = v.x * v.x + v.y * v.y + v.z * v.z + v.w * v.w;
#pragma unroll
    for (int off = 32; off; off >>= 1) {
        s += __shfl_down(s, off);
        ss += __shfl_down(ss, off);
    }
    if (lane == 0) {
        float mean = s * (1.f / 256.f);
        float var = ss * (1.f / 256.f) - mean * mean;
        mu[tok] = mean;
        rs[tok] = rsqrtf(var + 1e-5f);
    }
}

// ---------------------------------------------------------------------------
// Kernel 3: gx = LN(h)*g+b @ Wx + bg   (fp32 tiled GEMM, LN fused on A-load)
// M=32768 K=256 N=1024, tile 128x128, K-chunks of 64
// grid (M/128, N/128), 256 threads
// ---------------------------------------------------------------------------
__global__ __launch_bounds__(256, 2) void gemm_gx_kernel(
    const float* __restrict__ h, const float* __restrict__ mu, const float* __restrict__ rs,
    const float* __restrict__ lng, const float* __restrict__ lnb,
    const float* __restrict__ Wx, const float* __restrict__ bg, float* __restrict__ gx) {
    const int rowBase = blockIdx.x * 128, nBase = blockIdx.y * 128;
    const int tid = threadIdx.x;
    const int tx = tid & 15, ty = tid >> 4;
    __shared__ float As[64][132];  // k-major: As[k][row]
    __shared__ float Bs[64][132];  // k-major: Bs[k][col]
    float acc[8][8] = {{0.f}};
    float bgv[8];
#pragma unroll
    for (int j = 0; j < 8; ++j) bgv[j] = bg[nBase + tx + 16 * j];

    for (int kc = 0; kc < 256; kc += 64) {
        // A tile: 128 rows x 64 k, transformed by layernorm
#pragma unroll
        for (int it = 0; it < 8; ++it) {
            int f = it * 256 + tid;        // float4 index, 0..2047
            int row = f >> 4;              // 0..127
            int kp = (f & 15) << 2;        // 0..60
            const float4 hv = *(const float4*)(h + (size_t)(rowBase + row) * DD + kc + kp);
            float muv = mu[rowBase + row], rsv = rs[rowBase + row];
            const float4 gv = *(const float4*)(lng + kc + kp);
            const float4 bv = *(const float4*)(lnb + kc + kp);
            As[kp + 0][row] = (hv.x - muv) * rsv * gv.x + bv.x;
            As[kp + 1][row] = (hv.y - muv) * rsv * gv.y + bv.y;
            As[kp + 2][row] = (hv.z - muv) * rsv * gv.z + bv.z;
            As[kp + 3][row] = (hv.w - muv) * rsv * gv.w + bv.w;
        }
        // B tile: 64 k x 128 cols
#pragma unroll
        for (int it = 0; it < 8; ++it) {
            int f = it * 256 + tid;
            int kr = f >> 5;               // 0..63
            int cp = (f & 31) << 2;        // 0..124
            *(float4*)&Bs[kr][cp] = *(const float4*)(Wx + (size_t)(kc + kr) * ND4 + nBase + cp);
        }
        __syncthreads();
#pragma unroll 8
        for (int kk = 0; kk < 64; ++kk) {
            float a[8], b[8];
#pragma unroll
            for (int i = 0; i < 8; ++i) a[i] = As[kk][ty + 16 * i];
#pragma unroll
            for (int j = 0; j < 8; ++j) b[j] = Bs[kk][tx + 16 * j];
#pragma unroll
            for (int i = 0; i < 8; ++i)
#pragma unroll
                for (int j = 0; j < 8; ++j) acc[i][j] = fmaf(a[i], b[j], acc[i][j]);
        }
        __syncthreads();
    }
#pragma unroll
    for (int i = 0; i < 8; ++i) {
        size_t row = rowBase + ty + 16 * i;
#pragma unroll
        for (int j = 0; j < 8; ++j)
            gx[row * ND4 + nBase + tx + 16 * j] = acc[i][j] + bgv[j];
    }
}

// ---------------------------------------------------------------------------
// Kernel 4: the sLSTM scan for one layer.
// grid = 64 blocks (b = blk&15, q = blk>>4 = K-slice), 1024 threads (1 col each).
// Each thread holds Wh[64q..64q+63][col] in 64 VGPRs. Per step:
//   partial = w . hs[64q..+63]  -> publish as (tag<<32|fp32) relaxed agent atomic
//   gather 3 partner partials (exact-tag poll, parity double-buffered)
//   every WG redundantly computes all gates -> full h in LDS (no 2nd exchange)
// Zero fences needed: payload and tag travel in one 64-bit atom.
// ---------------------------------------------------------------------------
__global__ __launch_bounds__(1024, 4) void scan_kernel(
    const float* __restrict__ gx,           // [16][2048][1024]
    const float* __restrict__ Wh,           // [256][1024] layer slice
    float* __restrict__ h,                  // [16][2048][256] residual stream, updated in place
    unsigned long long* __restrict__ P,     // [2][16][4][1024] tagged partials
    int* __restrict__ abortFlag) {
    const int b = blockIdx.x & 15;
    const int q = blockIdx.x >> 4;          // 0..3
    const int col = threadIdx.x;            // 0..1023

    __shared__ float hs_lds[DD];
    __shared__ float gcol[ND4];

    // weights: Wh[64q+kk][col], kk=0..63  (coalesced across col)
    float w[64];
    const float* wp = Wh + (size_t)(q << 6) * ND4 + col;
#pragma unroll
    for (int kk = 0; kk < 64; ++kk) w[kk] = wp[(size_t)kk * ND4];

    if (col < DD) hs_lds[col] = 0.f;
    float c = 0.f, n = 0.f, m = 0.f;

    const float* gxp = gx + (size_t)b * SS * ND4 + col;
    float* hb = h + (size_t)b * SS * DD;
    unsigned long long* Pq[2];
    Pq[0] = P + ((size_t)(0 * 16 + b) * 4) * ND4;
    Pq[1] = P + ((size_t)(1 * 16 + b) * 4) * ND4;
    __syncthreads();

    for (int t = 0; t < SS; ++t) {
        const unsigned tag = (unsigned)(t + 1);
        unsigned long long* slotbase = Pq[t & 1];
        // prefetch step inputs (plain loads; latency hidden under fma + poll)
        float gxv = gxp[(size_t)t * ND4];
        float hin = 0.f;
        if (col < DD) hin = hb[(size_t)t * DD + col];

        // K-slice dot product from LDS broadcast reads
        const float4* hv4 = (const float4*)(hs_lds + (q << 6));
        float a0 = 0.f, a1 = 0.f, a2 = 0.f, a3 = 0.f;
#pragma unroll
        for (int k4 = 0; k4 < 16; ++k4) {
            float4 hv = hv4[k4];
            a0 = fmaf(w[4 * k4 + 0], hv.x, a0);
            a1 = fmaf(w[4 * k4 + 1], hv.y, a1);
            a2 = fmaf(w[4 * k4 + 2], hv.z, a2);
            a3 = fmaf(w[4 * k4 + 3], hv.w, a3);
        }
        float part = (a0 + a1) + (a2 + a3);

        // publish tagged partial
        unsigned long long pv = ((unsigned long long)tag << 32) | (unsigned long long)__float_as_uint(part);
        __hip_atomic_store(slotbase + (size_t)q * ND4 + col, pv, __ATOMIC_RELAXED, __HIP_MEMORY_SCOPE_AGENT);
        __asm__ volatile("" ::: "memory");  // keep store before the poll loop

        // gather partner partials
        float gsum = part + gxv;
#pragma unroll
        for (int dq = 1; dq < 4; ++dq) {
            int qq = (q + dq) & 3;
            unsigned long long* sl = slotbase + (size_t)qq * ND4 + col;
            unsigned long long v;
            int guard = 0;
            for (;;) {
                v = __hip_atomic_load(sl, __ATOMIC_RELAXED, __HIP_MEMORY_SCOPE_AGENT);
                if ((unsigned)(v >> 32) == tag) break;
                if ((++guard & 255) == 0) {
                    if (guard > (1 << 20) ||
                        __hip_atomic_load(abortFlag, __ATOMIC_RELAXED, __HIP_MEMORY_SCOPE_AGENT)) {
                        __hip_atomic_store(abortFlag, 1, __ATOMIC_RELAXED, __HIP_MEMORY_SCOPE_AGENT);
                        break;  // bail out (wrong answer, but no hang)
                    }
                    __builtin_amdgcn_s_sleep(1);
                }
            }
            gsum += __uint_as_float((unsigned)v);
        }

        __syncthreads();          // everyone done reading hs_lds / prev gcol
        gcol[col] = gsum;
        __syncthreads();
        if (col < DD) {
            float gi = gcol[col], gf = gcol[DD + col], gz = gcol[2 * DD + col], go = gcol[3 * DD + col];
            float mn = fmaxf(gf + m, gi);
            float ip = __expf(gi - mn);
            float fp = __expf(gf + m - mn);
            c = fp * c + ip * tanhf(gz);
            n = fp * n + ip;
            m = mn;
            float hval = (c / fmaxf(fabsf(n), 1.f)) * (1.f / (1.f + __expf(-go)));
            hs_lds[col] = hval;
            if (q == (col >> 6)) hb[(size_t)t * DD + col] = hin + hval;  // residual, spread across WGs
        }
        __syncthreads();
    }
}

// ---------------------------------------------------------------------------
// Kernel 5: out[b] = h[b][S-1][:] . fc_W + fc_b   (one wave per batch)
// ---------------------------------------------------------------------------
__global__ void final_kernel(const float* __restrict__ h, const float* __restrict__ fcW,
                             const float* __restrict__ fcb, float* __restrict__ out) {
    int b = blockIdx.x, lane = threadIdx.x;
    const float4 hv = *(const float4*)(h + ((size_t)b * SS + (SS - 1)) * DD + lane * 4);
    const float4 wv = *(const float4*)(fcW + lane * 4);
    float s = hv.x * wv.x + hv.y * wv.y + hv.z * wv.z + hv.w * wv.w;
#pragma unroll
    for (int off = 32; off; off >>= 1) s += __shfl_down(s, off);
    if (lane == 0) out[b] = s + fcb[0];
}

// ---------------------------------------------------------------------------
extern "C" void kernel_launch(void* const* d_in, const int* in_sizes, int n_in,
                              void* d_out, int out_size, void* d_ws, size_t ws_size,
                              hipStream_t stream) {
    const float* x   = (const float*)d_in[0];   // [16,2048]
    const float* tf  = (const float*)d_in[1];   // [16,2048,6]
    const float* inW = (const float*)d_in[2];   // [7,256]
    const float* inb = (const float*)d_in[3];   // [256]
    const float* lng = (const float*)d_in[4];   // [4,256]
    const float* lnb = (const float*)d_in[5];   // [4,256]
    const float* Wx  = (const float*)d_in[6];   // [4,256,1024]
    const float* Wh  = (const float*)d_in[7];   // [4,256,1024]
    const float* bg  = (const float*)d_in[8];   // [4,1024]
    const float* fcW = (const float*)d_in[9];   // [256,1]
    const float* fcb = (const float*)d_in[10];  // [1]
    float* out = (float*)d_out;

    // workspace layout (floats)
    const size_t nTok = (size_t)BB * SS;                  // 32768
    float* h  = (float*)d_ws;                             // 8,388,608 f
    float* mu = h + nTok * DD;                            // 32768 f
    float* rs = mu + nTok;                                // 32768 f
    float* gxb = rs + nTok;                               // 33,554,432 f
    unsigned long long* P = (unsigned long long*)(gxb + nTok * ND4);  // 131072 u64
    int* abortFlag = (int*)(P + 2 * 16 * 4 * ND4);

    const size_t needed = (size_t)((char*)(abortFlag + 1) - (char*)d_ws);
    if (ws_size < needed) return;  // fail visibly (zeros) instead of corrupting

    hipMemsetAsync(abortFlag, 0, sizeof(int), stream);    // ws is poisoned 0xAA each call

    embed_kernel<<<nTok, DD, 0, stream>>>(x, tf, inW, inb, h);

    for (int l = 0; l < LL; ++l) {
        ln_stats_kernel<<<nTok / 4, 256, 0, stream>>>(h, mu, rs);
        gemm_gx_kernel<<<dim3(nTok / 128, ND4 / 128), 256, 0, stream>>>(
            h, mu, rs, lng + l * DD, lnb + l * DD,
            Wx + (size_t)l * DD * ND4, bg + l * ND4, gxb);
        scan_kernel<<<64, 1024, 0, stream>>>(
            gxb, Wh + (size_t)l * DD * ND4, h, P, abortFlag);
    }

    final_kernel<<<BB, 64, 0, stream>>>(h, fcW, fcb, out);
    (void)in_sizes; (void)n_in; (void)out_size;
}